// Round 6
// baseline (106.694 us; speedup 1.0000x reference)
//
#include <hip/hip_runtime.h>
#include <math.h>

#define NEG_INF (-INFINITY)

__device__ __forceinline__ float nll3(float l0, float l1, float l2) {
    float m = fmaxf(l0, fmaxf(l1, l2));
    float e0 = __expf(l0 - m);
    float e1 = __expf(l1 - m);
    float e2 = __expf(l2 - m);
    return __logf(e0 + e1 + e2) - (l0 - m);
}

// ---------------------------------------------------------------------------
// Separable, barrier-free, atomic-free negative focal loss strip.
// A "unit" is WL lanes covering one w-row (WL == W). It owns a
// (TD x NR x WL) output strip and slides along d. Per d-plane:
//   - NI = NR+2 input rows: 1 nll3 each (separable max)
//   - row-max via 2 lane shuffles (w-edges masked)
//   - plane-max for output row r = max(rm[r], rm[r+1], rm[r+2])
//   - 3-deep register window along d completes the 3x3x3 NMS max
// Next plane's loads are issued before current-plane compute (1-deep reg
// pipeline); TLP (6.8 waves/SIMD) covers the rest of the latency.
// Partial (loss,cnt) goes to a PRIVATE float2 slot — no atomics.
// ---------------------------------------------------------------------------
template<int WL, int NR, int TD, int D, int H, int W>
__device__ void neg_strip(int uid, int lane,
                          const float* __restrict__ logit,
                          const float* __restrict__ pg,
                          float2* __restrict__ slot) {
    constexpr int NI = NR + 2;
    constexpr int HG = H / NR;
    constexpr int DT = D / TD;
    const int w = lane & (WL - 1);

    int t = uid;
    const int hg = t % HG; t /= HG;
    const int dt = t % DT; t /= DT;
    const int ba = t;                       // b*3 + a (A == 3)
    const int a = ba % 3, b = ba / 3;
    const int h0 = hg * NR, d0 = dt * TD;

    const long S = (long)D * H * W;
    const float* lb  = logit + ((long)b * 9 + a) * S;   // class-0 plane
    const long  cs   = 3 * S;                           // A*S
    const float* pgb = pg + (long)ba * S;

    bool hv[NI]; int hoff[NI];
#pragma unroll
    for (int j = 0; j < NI; ++j) {
        int hh = h0 - 1 + j;
        hv[j] = (hh >= 0) && (hh < H);
        hoff[j] = hh * W + w;
    }

    float cur[NI][3] = {}, nxt[NI][3] = {};
    float vm0[NR], vm1[NR], c1r[NR], pgc[NR] = {}, pgn[NR] = {};
#pragma unroll
    for (int r = 0; r < NR; ++r) { vm0[r] = NEG_INF; vm1[r] = NEG_INF; c1r[r] = 0.f; }

    bool dv_cur = (d0 - 1 >= 0);
    if (dv_cur) {
        const float* p0 = lb + (long)(d0 - 1) * (H * W);
#pragma unroll
        for (int j = 0; j < NI; ++j) if (hv[j]) {
            const float* p = p0 + hoff[j];
            cur[j][0] = p[0]; cur[j][1] = p[cs]; cur[j][2] = p[2 * cs];
        }
    }

    float loss = 0.f, cnt = 0.f;

#pragma unroll
    for (int s = 0; s <= TD + 1; ++s) {
        const int d = d0 - 1 + s;
        const int dn = d + 1;
        const bool dv_nxt = (dn < D);
        // issue next plane's loads + this plane's pg BEFORE current compute
        if (s <= TD) {
            if (dv_nxt) {
                const float* p0 = lb + (long)dn * (H * W);
#pragma unroll
                for (int j = 0; j < NI; ++j) if (hv[j]) {
                    const float* p = p0 + hoff[j];
                    nxt[j][0] = p[0]; nxt[j][1] = p[cs]; nxt[j][2] = p[2 * cs];
                }
            }
            if (s >= 1) {                       // d in [d0, d0+TD-1] < D
                const float* pp = pgb + (long)d * (H * W);
#pragma unroll
                for (int r = 0; r < NR; ++r)
                    pgn[r] = pp[(h0 + r) * W + w];
            }
        }

        float nv[NI], rm[NI];
#pragma unroll
        for (int j = 0; j < NI; ++j)
            nv[j] = (dv_cur && hv[j]) ? nll3(cur[j][0], cur[j][1], cur[j][2])
                                      : NEG_INF;
#pragma unroll
        for (int j = 0; j < NI; ++j) {
            float lf = __shfl(nv[j], lane - 1);
            float rt = __shfl(nv[j], lane + 1);
            lf = (w == 0)      ? NEG_INF : lf;   // masks also protect the
            rt = (w == WL - 1) ? NEG_INF : rt;   // WL=32 half-wave boundary
            rm[j] = fmaxf(nv[j], fmaxf(lf, rt));
        }
#pragma unroll
        for (int r = 0; r < NR; ++r) {
            float hw2 = fmaxf(rm[r], fmaxf(rm[r + 1], rm[r + 2]));
            float cc  = nv[r + 1];
            if (s >= 2 && pgc[r] == -1.0f) {     // center plane d0+s-2
                float mp = fmaxf(vm0[r], fmaxf(vm1[r], hw2));
                if (mp == c1r[r]) {
                    float pn = __expf(-c1r[r]);
                    float wn = (1.f - pn) * (1.f - pn);
                    loss += c1r[r] * wn;
                    cnt  += wn;
                }
            }
            vm0[r] = vm1[r]; vm1[r] = hw2; c1r[r] = cc;
        }
#pragma unroll
        for (int r = 0; r < NR; ++r) pgc[r] = pgn[r];
        dv_cur = dv_nxt;
#pragma unroll
        for (int j = 0; j < NI; ++j) {
            cur[j][0] = nxt[j][0]; cur[j][1] = nxt[j][1]; cur[j][2] = nxt[j][2];
        }
    }

#pragma unroll
    for (int off = WL / 2; off > 0; off >>= 1) {
        loss += __shfl_down(loss, off, WL);
        cnt  += __shfl_down(cnt, off, WL);
    }
    if (w == 0) slot[uid] = make_float2(loss, cnt);
}

// ---------------------------------------------------------------------------
// Positive gathers: 8 waves per level, 1 item per lane (B*P = 512).
// ---------------------------------------------------------------------------
__device__ void pos_wave8(int sub, int lane,
                          const float* __restrict__ logit,
                          const float* __restrict__ prob_gt,
                          const int* __restrict__ coord,
                          const float* __restrict__ wcls,
                          float2* __restrict__ slot,
                          int D, int H, int W) {
    const int A = 3, P = 128;
    const long S = (long)D * H * W;
    const int i = sub * 64 + lane;          // < 512
    const int b = i / P;
    const int* c = coord + (long)i * 4;
    const int a = c[0];
    float loss = 0.f, cnt = 0.f;
    if (a > -1) {
        const int d = c[1], h = c[2], w = c[3];
        const long s = ((long)d * H + h) * W + w;
        const int cls = (int)prob_gt[((long)b * A + a) * S + s];
        const float* lp = logit + ((long)b * 3 * A + a) * S + s;
        float l0 = lp[0];
        float l1 = lp[(long)A * S];
        float l2 = lp[2L * A * S];
        float m = fmaxf(l0, fmaxf(l1, l2));
        float e0 = __expf(l0 - m);
        float e1 = __expf(l1 - m);
        float e2 = __expf(l2 - m);
        float lsum = __logf(e0 + e1 + e2);
        float lc = (cls == 0) ? l0 : ((cls == 1) ? l1 : l2);
        float lpc = (lc - m) - lsum;
        float pt = __expf(lpc);
        float wp = (1.f - pt) * (1.f - pt) * wcls[cls];
        loss = (-lpc) * wp;
        cnt = wp;
    }
#pragma unroll
    for (int off = 32; off > 0; off >>= 1) {
        loss += __shfl_down(loss, off);
        cnt  += __shfl_down(cnt, off);
    }
    if (lane == 0) *slot = make_float2(loss, cnt);
}

// ---------------------------------------------------------------------------
// Work split (wave-indexed, barrier-free):
//   L0 neg: WL=64, NR=2, TD=4 -> 12*32*16 = 6144 units, 1/wave
//   L1 neg: WL=32, NR=2, TD=4 -> 12*16*8  = 1536 units, 2/wave -> 768 waves
//   pos:    8 + 8 waves
// Total 6928 waves -> 1732 blocks, ~6.8 waves/SIMD of latency-hiding TLP.
// ---------------------------------------------------------------------------
#define NU0 6144
#define NW0 6144
#define NU1 1536
#define NW1 768
#define NWP 16
#define NSLOT (NU0 + NU1 + NWP)
#define TOTAL_WAVES (NW0 + NW1 + NWP)   // 6928 -> 1732 blocks

__global__ __launch_bounds__(256)
void mega_kernel(const float* __restrict__ logit0,
                 const float* __restrict__ logit1,
                 const float* __restrict__ pg0,
                 const float* __restrict__ pg1,
                 const int* __restrict__ coord0,
                 const int* __restrict__ coord1,
                 const float* __restrict__ wcls,
                 float2* __restrict__ ws) {
    const int gw = blockIdx.x * 4 + (threadIdx.x >> 6);
    const int lane = threadIdx.x & 63;
    float2* wsneg = ws;
    float2* wspos = ws + (NU0 + NU1);
    if (gw < NW0) {
        neg_strip<64, 2, 4, 64, 64, 64>(gw, lane, logit0, pg0, wsneg);
    } else if (gw < NW0 + NW1) {
        const int u = (gw - NW0) * 2 + (lane >> 5);
        neg_strip<32, 2, 4, 32, 32, 32>(u, lane, logit1, pg1, wsneg + NU0);
    } else if (gw < NW0 + NW1 + 8) {
        const int sub = gw - NW0 - NW1;
        pos_wave8(sub, lane, logit0, pg0, coord0, wcls, wspos + sub, 64, 64, 64);
    } else if (gw < NW0 + NW1 + 16) {
        const int sub = gw - NW0 - NW1 - 8;
        pos_wave8(sub, lane, logit1, pg1, coord1, wcls, wspos + 8 + sub, 32, 32, 32);
    }
}

// ---------------------------------------------------------------------------
// Final reduction: one 1024-thread block sums all slots, writes out[0..3].
// ---------------------------------------------------------------------------
__global__ __launch_bounds__(1024)
void final_reduce(const float2* __restrict__ ws, float* __restrict__ out) {
    const float2* wsneg = ws;
    const float2* wspos = ws + (NU0 + NU1);
    float ln = 0.f, cn = 0.f, lp = 0.f, cp = 0.f;
    for (int i = threadIdx.x; i < NU0 + NU1; i += 1024) {
        float2 v = wsneg[i]; ln += v.x; cn += v.y;
    }
    if (threadIdx.x < NWP) {
        float2 v = wspos[threadIdx.x]; lp = v.x; cp = v.y;
    }
#pragma unroll
    for (int off = 32; off > 0; off >>= 1) {
        ln += __shfl_down(ln, off); cn += __shfl_down(cn, off);
        lp += __shfl_down(lp, off); cp += __shfl_down(cp, off);
    }
    __shared__ float s[16][4];
    const int wv = threadIdx.x >> 6;
    if ((threadIdx.x & 63) == 0) {
        s[wv][0] = ln; s[wv][1] = cn; s[wv][2] = lp; s[wv][3] = cp;
    }
    __syncthreads();
    if (threadIdx.x == 0) {
        float a = 0.f, b = 0.f, c = 0.f, d = 0.f;
#pragma unroll
        for (int i = 0; i < 16; ++i) {
            a += s[i][0]; b += s[i][1]; c += s[i][2]; d += s[i][3];
        }
        out[0] = c;   // loss_pos
        out[1] = a;   // loss_neg
        out[2] = d;   // count_pos
        out[3] = b;   // count_neg
    }
}

extern "C" void kernel_launch(void* const* d_in, const int* in_sizes, int n_in,
                              void* d_out, int out_size, void* d_ws, size_t ws_size,
                              hipStream_t stream) {
    const float* logit0   = (const float*)d_in[0];
    const float* logit1   = (const float*)d_in[1];
    const float* prob_gt0 = (const float*)d_in[2];
    const float* prob_gt1 = (const float*)d_in[3];
    const int*   coord0   = (const int*)d_in[4];
    const int*   coord1   = (const int*)d_in[5];
    const float* wcls     = (const float*)d_in[6];
    float* out = (float*)d_out;
    float2* ws = (float2*)d_ws;

    mega_kernel<<<TOTAL_WAVES / 4, 256, 0, stream>>>(
        logit0, logit1, prob_gt0, prob_gt1, coord0, coord1, wcls, ws);
    final_reduce<<<1, 1024, 0, stream>>>(ws, out);
}

// Round 7
// 106.578 us; speedup vs baseline: 1.0011x; 1.0011x over previous
//
#include <hip/hip_runtime.h>
#include <math.h>

#define NEG_INF (-INFINITY)

__device__ __forceinline__ float nll3(float l0, float l1, float l2) {
    float m = fmaxf(l0, fmaxf(l1, l2));
    float e0 = __expf(l0 - m);
    float e1 = __expf(l1 - m);
    float e2 = __expf(l2 - m);
    return __logf(e0 + e1 + e2) - (l0 - m);
}

// ---------------------------------------------------------------------------
// Vectorized, barrier-free, atomic-free, UNCONDITIONALLY-loading neg strip.
// Wave layout: NG = 64/(W/4) row-groups x LR = W/4 lanes; lane g covers input
// row h0-1+g, 4 consecutive w's (float4). Groups 0..NR-1 emit output rows
// h0..h0+NR-1. Slide along d, TD output planes per wave.
// ALL global loads are unconditional (addresses clamped, values selected to
// -inf afterwards) inside a fully-unrolled step loop -> compiler can emit
// fine-grained s_waitcnt vmcnt(N), keeping the 1-step prefetch pipeline live.
// ---------------------------------------------------------------------------
template<int W, int NR, int TD, int D, int H>
__device__ void neg_strip_v(int uid, int lane,
                            const float* __restrict__ logit,
                            const float* __restrict__ pg,
                            float2* __restrict__ slot) {
    constexpr int LR = W / 4;          // lanes per row
    constexpr int NG = 64 / LR;        // row groups per wave
    constexpr int NI = NR + 2;         // input rows used (<= NG)
    constexpr int HG = H / NR;
    constexpr int DT = D / TD;
    const int q = lane % LR;
    const int g = lane / LR;

    int t = uid;
    const int hg = t % HG; t /= HG;
    const int dt = t % DT; t /= DT;
    const int ba = t;                  // b*3 + a (A == 3)
    const int a = ba % 3, b = ba / 3;
    const int h0 = hg * NR, d0 = dt * TD;

    const long S = (long)D * H * W;
    const float* lb  = logit + ((long)b * 9 + a) * S;   // class-0 plane
    const long  cs   = 3 * S;                           // A*S
    const float* pgb = pg + (long)ba * S;

    // this lane's input row (clamped address + validity flag)
    const int jrow = h0 - 1 + g;
    const bool hv = (jrow >= 0) && (jrow < H) && (g < NI);
    const int hcl = min(max(jrow, 0), H - 1);
    const int rowoff = hcl * W + 4 * q;
    // pg row (groups >= NR duplicate row h0+NR-1; unused)
    const int prowoff = (h0 + min(g, NR - 1)) * W + 4 * q;

    float4 c0, c1v, c2, n0, n1, n2, pgn;
    bool dvc = (d0 - 1 >= 0);
    {
        const float* p = lb + (long)max(d0 - 1, 0) * (H * W) + rowoff;
        c0  = *(const float4*)(p);
        c1v = *(const float4*)(p + cs);
        c2  = *(const float4*)(p + 2 * cs);
    }

    float vm0[4], vm1[4], cc1[4], pgc[4];
#pragma unroll
    for (int i = 0; i < 4; ++i) {
        vm0[i] = NEG_INF; vm1[i] = NEG_INF; cc1[i] = 0.f; pgc[i] = 0.f;
    }

    float loss = 0.f, cnt = 0.f;

#pragma unroll
    for (int s = 0; s <= TD + 1; ++s) {                 // s is compile-time
        const int d = d0 - 1 + s;
        const bool dvn = (s <= TD - 1) || (d + 1 < D);  // d+1 validity
        // ---- unconditional prefetches (static guards only) ----
        if (s <= TD) {                                  // compile-time guard
            const float* p = lb + (long)min(d + 1, D - 1) * (H * W) + rowoff;
            n0 = *(const float4*)(p);
            n1 = *(const float4*)(p + cs);
            n2 = *(const float4*)(p + 2 * cs);
            pgn = *(const float4*)(pgb + (long)min(max(d, 0), D - 1) * (H * W)
                                   + prowoff);
        }

        // ---- nll of current plane (values selected, loads were uncond.) ----
        float nvv[4];
        {
            const bool vv = dvc && hv;
            nvv[0] = vv ? nll3(c0.x, c1v.x, c2.x) : NEG_INF;
            nvv[1] = vv ? nll3(c0.y, c1v.y, c2.y) : NEG_INF;
            nvv[2] = vv ? nll3(c0.z, c1v.z, c2.z) : NEG_INF;
            nvv[3] = vv ? nll3(c0.w, c1v.w, c2.w) : NEG_INF;
        }

        // ---- in-row 3-wide max (in-lane + 2 edge shuffles) ----
        float le = __shfl(nvv[3], lane - 1);
        float re = __shfl(nvv[0], lane + 1);
        le = (q == 0)      ? NEG_INF : le;
        re = (q == LR - 1) ? NEG_INF : re;
        float rm[4];
        rm[0] = fmaxf(le,     fmaxf(nvv[0], nvv[1]));
        rm[1] = fmaxf(nvv[0], fmaxf(nvv[1], nvv[2]));
        rm[2] = fmaxf(nvv[1], fmaxf(nvv[2], nvv[3]));
        rm[3] = fmaxf(nvv[2], fmaxf(nvv[3], re));

        // ---- cross-row: group r gets rows r+1, r+2 and center row r+1 ----
        float rmA[4], rmB[4], ctr[4];
#pragma unroll
        for (int i = 0; i < 4; ++i) {
            rmA[i] = __shfl(rm[i],  lane + LR);
            rmB[i] = __shfl(rm[i],  lane + 2 * LR);
            ctr[i] = __shfl(nvv[i], lane + LR);
        }

        // ---- 3-deep d-window + emit (groups < NR only) ----
#pragma unroll
        for (int i = 0; i < 4; ++i) {
            float hw2 = fmaxf(rm[i], fmaxf(rmA[i], rmB[i]));
            if (s >= 2 && g < NR && pgc[i] == -1.0f) {
                float mp = fmaxf(vm0[i], fmaxf(vm1[i], hw2));
                if (mp == cc1[i]) {
                    float pn = __expf(-cc1[i]);
                    float wn = (1.f - pn) * (1.f - pn);
                    loss += cc1[i] * wn;
                    cnt  += wn;
                }
            }
            vm0[i] = vm1[i]; vm1[i] = hw2; cc1[i] = ctr[i];
        }
        pgc[0] = pgn.x; pgc[1] = pgn.y; pgc[2] = pgn.z; pgc[3] = pgn.w;
        dvc = dvn;
        c0 = n0; c1v = n1; c2 = n2;
    }

    // wave reduce (only groups < NR hold nonzero) + private slot write
#pragma unroll
    for (int off = 32; off > 0; off >>= 1) {
        loss += __shfl_down(loss, off);
        cnt  += __shfl_down(cnt, off);
    }
    if (lane == 0) slot[uid] = make_float2(loss, cnt);
}

// ---------------------------------------------------------------------------
// Positive gathers: 8 waves per level, 1 item per lane (B*P = 512).
// ---------------------------------------------------------------------------
__device__ void pos_wave8(int sub, int lane,
                          const float* __restrict__ logit,
                          const float* __restrict__ prob_gt,
                          const int* __restrict__ coord,
                          const float* __restrict__ wcls,
                          float2* __restrict__ slot,
                          int D, int H, int W) {
    const int A = 3, P = 128;
    const long S = (long)D * H * W;
    const int i = sub * 64 + lane;          // < 512
    const int b = i / P;
    const int* c = coord + (long)i * 4;
    const int a = c[0];
    float loss = 0.f, cnt = 0.f;
    if (a > -1) {
        const int d = c[1], h = c[2], w = c[3];
        const long s = ((long)d * H + h) * W + w;
        const int cls = (int)prob_gt[((long)b * A + a) * S + s];
        const float* lp = logit + ((long)b * 3 * A + a) * S + s;
        float l0 = lp[0];
        float l1 = lp[(long)A * S];
        float l2 = lp[2L * A * S];
        float m = fmaxf(l0, fmaxf(l1, l2));
        float e0 = __expf(l0 - m);
        float e1 = __expf(l1 - m);
        float e2 = __expf(l2 - m);
        float lsum = __logf(e0 + e1 + e2);
        float lc = (cls == 0) ? l0 : ((cls == 1) ? l1 : l2);
        float lpc = (lc - m) - lsum;
        float pt = __expf(lpc);
        float wp = (1.f - pt) * (1.f - pt) * wcls[cls];
        loss = (-lpc) * wp;
        cnt = wp;
    }
#pragma unroll
    for (int off = 32; off > 0; off >>= 1) {
        loss += __shfl_down(loss, off);
        cnt  += __shfl_down(cnt, off);
    }
    if (lane == 0) *slot = make_float2(loss, cnt);
}

// ---------------------------------------------------------------------------
// Work split (wave-indexed, barrier-free):
//   L0: W=64 -> 16 lanes/row x 4 groups, NR=2, TD=4 -> 12*32*16 = 6144 waves
//   L1: W=32 ->  8 lanes/row x 8 groups, NR=4, TD=4 -> 12*8*8   =  768 waves
//   pos: 8 + 8 waves
// ---------------------------------------------------------------------------
#define NW0 6144
#define NW1 768
#define NWP 16
#define NUNEG (NW0 + NW1)
#define TOTAL_WAVES (NW0 + NW1 + NWP)   // 6928 -> 1732 blocks

__global__ __launch_bounds__(256)
void mega_kernel(const float* __restrict__ logit0,
                 const float* __restrict__ logit1,
                 const float* __restrict__ pg0,
                 const float* __restrict__ pg1,
                 const int* __restrict__ coord0,
                 const int* __restrict__ coord1,
                 const float* __restrict__ wcls,
                 float2* __restrict__ ws) {
    const int gw = blockIdx.x * 4 + (threadIdx.x >> 6);
    const int lane = threadIdx.x & 63;
    float2* wsneg = ws;
    float2* wspos = ws + NUNEG;
    if (gw < NW0) {
        neg_strip_v<64, 2, 4, 64, 64>(gw, lane, logit0, pg0, wsneg);
    } else if (gw < NW0 + NW1) {
        neg_strip_v<32, 4, 4, 32, 32>(gw - NW0, lane, logit1, pg1, wsneg + NW0);
    } else if (gw < NW0 + NW1 + 8) {
        const int sub = gw - NW0 - NW1;
        pos_wave8(sub, lane, logit0, pg0, coord0, wcls, wspos + sub, 64, 64, 64);
    } else if (gw < NW0 + NW1 + 16) {
        const int sub = gw - NW0 - NW1 - 8;
        pos_wave8(sub, lane, logit1, pg1, coord1, wcls, wspos + 8 + sub, 32, 32, 32);
    }
}

// ---------------------------------------------------------------------------
// Final reduction: one 1024-thread block sums all slots, writes out[0..3].
// ---------------------------------------------------------------------------
__global__ __launch_bounds__(1024)
void final_reduce(const float2* __restrict__ ws, float* __restrict__ out) {
    const float2* wsneg = ws;
    const float2* wspos = ws + NUNEG;
    float ln = 0.f, cn = 0.f, lp = 0.f, cp = 0.f;
    for (int i = threadIdx.x; i < NUNEG; i += 1024) {
        float2 v = wsneg[i]; ln += v.x; cn += v.y;
    }
    if (threadIdx.x < NWP) {
        float2 v = wspos[threadIdx.x]; lp = v.x; cp = v.y;
    }
#pragma unroll
    for (int off = 32; off > 0; off >>= 1) {
        ln += __shfl_down(ln, off); cn += __shfl_down(cn, off);
        lp += __shfl_down(lp, off); cp += __shfl_down(cp, off);
    }
    __shared__ float s[16][4];
    const int wv = threadIdx.x >> 6;
    if ((threadIdx.x & 63) == 0) {
        s[wv][0] = ln; s[wv][1] = cn; s[wv][2] = lp; s[wv][3] = cp;
    }
    __syncthreads();
    if (threadIdx.x == 0) {
        float a = 0.f, b = 0.f, c = 0.f, d = 0.f;
#pragma unroll
        for (int i = 0; i < 16; ++i) {
            a += s[i][0]; b += s[i][1]; c += s[i][2]; d += s[i][3];
        }
        out[0] = c;   // loss_pos
        out[1] = a;   // loss_neg
        out[2] = d;   // count_pos
        out[3] = b;   // count_neg
    }
}

extern "C" void kernel_launch(void* const* d_in, const int* in_sizes, int n_in,
                              void* d_out, int out_size, void* d_ws, size_t ws_size,
                              hipStream_t stream) {
    const float* logit0   = (const float*)d_in[0];
    const float* logit1   = (const float*)d_in[1];
    const float* prob_gt0 = (const float*)d_in[2];
    const float* prob_gt1 = (const float*)d_in[3];
    const int*   coord0   = (const int*)d_in[4];
    const int*   coord1   = (const int*)d_in[5];
    const float* wcls     = (const float*)d_in[6];
    float* out = (float*)d_out;
    float2* ws = (float2*)d_ws;

    mega_kernel<<<TOTAL_WAVES / 4, 256, 0, stream>>>(
        logit0, logit1, prob_gt0, prob_gt1, coord0, coord1, wcls, ws);
    final_reduce<<<1, 1024, 0, stream>>>(ws, out);
}

// Round 8
// 106.451 us; speedup vs baseline: 1.0023x; 1.0012x over previous
//
#include <hip/hip_runtime.h>
#include <math.h>

#define NEG_INF (-INFINITY)

__device__ __forceinline__ float nll3(float l0, float l1, float l2) {
    float m = fmaxf(l0, fmaxf(l1, l2));
    float e0 = __expf(l0 - m);
    float e1 = __expf(l1 - m);
    float e2 = __expf(l2 - m);
    return __logf(e0 + e1 + e2) - (l0 - m);
}

// ---------------------------------------------------------------------------
// Vectorized, barrier-free, atomic-free, unconditionally-loading neg strip.
// (identical to previous round — see R7 notes)
// ---------------------------------------------------------------------------
template<int W, int NR, int TD, int D, int H>
__device__ void neg_strip_v(int uid, int lane,
                            const float* __restrict__ logit,
                            const float* __restrict__ pg,
                            float2* __restrict__ slot) {
    constexpr int LR = W / 4;          // lanes per row
    constexpr int NI = NR + 2;         // input rows used
    constexpr int HG = H / NR;
    constexpr int DT = D / TD;
    const int q = lane % LR;
    const int g = lane / LR;

    int t = uid;
    const int hg = t % HG; t /= HG;
    const int dt = t % DT; t /= DT;
    const int ba = t;                  // b*3 + a (A == 3)
    const int a = ba % 3, b = ba / 3;
    const int h0 = hg * NR, d0 = dt * TD;

    const long S = (long)D * H * W;
    const float* lb  = logit + ((long)b * 9 + a) * S;   // class-0 plane
    const long  cs   = 3 * S;                           // A*S
    const float* pgb = pg + (long)ba * S;

    const int jrow = h0 - 1 + g;
    const bool hv = (jrow >= 0) && (jrow < H) && (g < NI);
    const int hcl = min(max(jrow, 0), H - 1);
    const int rowoff = hcl * W + 4 * q;
    const int prowoff = (h0 + min(g, NR - 1)) * W + 4 * q;

    float4 c0, c1v, c2, n0, n1, n2, pgn;
    bool dvc = (d0 - 1 >= 0);
    {
        const float* p = lb + (long)max(d0 - 1, 0) * (H * W) + rowoff;
        c0  = *(const float4*)(p);
        c1v = *(const float4*)(p + cs);
        c2  = *(const float4*)(p + 2 * cs);
    }

    float vm0[4], vm1[4], cc1[4], pgc[4];
#pragma unroll
    for (int i = 0; i < 4; ++i) {
        vm0[i] = NEG_INF; vm1[i] = NEG_INF; cc1[i] = 0.f; pgc[i] = 0.f;
    }

    float loss = 0.f, cnt = 0.f;

#pragma unroll
    for (int s = 0; s <= TD + 1; ++s) {                 // s is compile-time
        const int d = d0 - 1 + s;
        const bool dvn = (s <= TD - 1) || (d + 1 < D);
        if (s <= TD) {                                  // compile-time guard
            const float* p = lb + (long)min(d + 1, D - 1) * (H * W) + rowoff;
            n0 = *(const float4*)(p);
            n1 = *(const float4*)(p + cs);
            n2 = *(const float4*)(p + 2 * cs);
            pgn = *(const float4*)(pgb + (long)min(max(d, 0), D - 1) * (H * W)
                                   + prowoff);
        }

        float nvv[4];
        {
            const bool vv = dvc && hv;
            nvv[0] = vv ? nll3(c0.x, c1v.x, c2.x) : NEG_INF;
            nvv[1] = vv ? nll3(c0.y, c1v.y, c2.y) : NEG_INF;
            nvv[2] = vv ? nll3(c0.z, c1v.z, c2.z) : NEG_INF;
            nvv[3] = vv ? nll3(c0.w, c1v.w, c2.w) : NEG_INF;
        }

        float le = __shfl(nvv[3], lane - 1);
        float re = __shfl(nvv[0], lane + 1);
        le = (q == 0)      ? NEG_INF : le;
        re = (q == LR - 1) ? NEG_INF : re;
        float rm[4];
        rm[0] = fmaxf(le,     fmaxf(nvv[0], nvv[1]));
        rm[1] = fmaxf(nvv[0], fmaxf(nvv[1], nvv[2]));
        rm[2] = fmaxf(nvv[1], fmaxf(nvv[2], nvv[3]));
        rm[3] = fmaxf(nvv[2], fmaxf(nvv[3], re));

        float rmA[4], rmB[4], ctr[4];
#pragma unroll
        for (int i = 0; i < 4; ++i) {
            rmA[i] = __shfl(rm[i],  lane + LR);
            rmB[i] = __shfl(rm[i],  lane + 2 * LR);
            ctr[i] = __shfl(nvv[i], lane + LR);
        }

#pragma unroll
        for (int i = 0; i < 4; ++i) {
            float hw2 = fmaxf(rm[i], fmaxf(rmA[i], rmB[i]));
            if (s >= 2 && g < NR && pgc[i] == -1.0f) {
                float mp = fmaxf(vm0[i], fmaxf(vm1[i], hw2));
                if (mp == cc1[i]) {
                    float pn = __expf(-cc1[i]);
                    float wn = (1.f - pn) * (1.f - pn);
                    loss += cc1[i] * wn;
                    cnt  += wn;
                }
            }
            vm0[i] = vm1[i]; vm1[i] = hw2; cc1[i] = ctr[i];
        }
        pgc[0] = pgn.x; pgc[1] = pgn.y; pgc[2] = pgn.z; pgc[3] = pgn.w;
        dvc = dvn;
        c0 = n0; c1v = n1; c2 = n2;
    }

#pragma unroll
    for (int off = 32; off > 0; off >>= 1) {
        loss += __shfl_down(loss, off);
        cnt  += __shfl_down(cnt, off);
    }
    if (lane == 0) slot[uid] = make_float2(loss, cnt);
}

// ---------------------------------------------------------------------------
// Positive gathers: 8 waves per level, 1 item per lane (B*P = 512).
// ---------------------------------------------------------------------------
__device__ void pos_wave8(int sub, int lane,
                          const float* __restrict__ logit,
                          const float* __restrict__ prob_gt,
                          const int* __restrict__ coord,
                          const float* __restrict__ wcls,
                          float2* __restrict__ slot,
                          int D, int H, int W) {
    const int A = 3, P = 128;
    const long S = (long)D * H * W;
    const int i = sub * 64 + lane;          // < 512
    const int b = i / P;
    const int* c = coord + (long)i * 4;
    const int a = c[0];
    float loss = 0.f, cnt = 0.f;
    if (a > -1) {
        const int d = c[1], h = c[2], w = c[3];
        const long s = ((long)d * H + h) * W + w;
        const int cls = (int)prob_gt[((long)b * A + a) * S + s];
        const float* lp = logit + ((long)b * 3 * A + a) * S + s;
        float l0 = lp[0];
        float l1 = lp[(long)A * S];
        float l2 = lp[2L * A * S];
        float m = fmaxf(l0, fmaxf(l1, l2));
        float e0 = __expf(l0 - m);
        float e1 = __expf(l1 - m);
        float e2 = __expf(l2 - m);
        float lsum = __logf(e0 + e1 + e2);
        float lc = (cls == 0) ? l0 : ((cls == 1) ? l1 : l2);
        float lpc = (lc - m) - lsum;
        float pt = __expf(lpc);
        float wp = (1.f - pt) * (1.f - pt) * wcls[cls];
        loss = (-lpc) * wp;
        cnt = wp;
    }
#pragma unroll
    for (int off = 32; off > 0; off >>= 1) {
        loss += __shfl_down(loss, off);
        cnt  += __shfl_down(cnt, off);
    }
    if (lane == 0) *slot = make_float2(loss, cnt);
}

// ---------------------------------------------------------------------------
// Work split (wave-indexed, barrier-free):
//   L0: 12*32*16 = 6144 waves   L1: 12*8*8 = 768 waves   pos: 16 waves
// XCD-locality swizzle: assuming xcd = blockIdx % 8, remap so each XCD gets
// a CONTIGUOUS run of logical blocks -> adjacent-hg waves (which share halo
// rows and d-planes) run on the same XCD and halo re-reads hit the local L2
// instead of crossing to L3.
// ---------------------------------------------------------------------------
#define NW0 6144
#define NW1 768
#define NWP 16
#define NUNEG (NW0 + NW1)
#define REAL_WAVES (NW0 + NW1 + NWP)    // 6928
#define NBLK 1736                        // 8 * 217 (padded; 1732 real)
#define NBX 217

__global__ __launch_bounds__(256)
void mega_kernel(const float* __restrict__ logit0,
                 const float* __restrict__ logit1,
                 const float* __restrict__ pg0,
                 const float* __restrict__ pg1,
                 const int* __restrict__ coord0,
                 const int* __restrict__ coord1,
                 const float* __restrict__ wcls,
                 float2* __restrict__ ws) {
    const int bid = blockIdx.x;
    const int lblock = (bid & 7) * NBX + (bid >> 3);   // contiguous per XCD
    const int gw = lblock * 4 + (threadIdx.x >> 6);
    const int lane = threadIdx.x & 63;
    if (gw >= REAL_WAVES) return;
    float2* wsneg = ws;
    float2* wspos = ws + NUNEG;
    if (gw < NW0) {
        neg_strip_v<64, 2, 4, 64, 64>(gw, lane, logit0, pg0, wsneg);
    } else if (gw < NW0 + NW1) {
        neg_strip_v<32, 4, 4, 32, 32>(gw - NW0, lane, logit1, pg1, wsneg + NW0);
    } else if (gw < NW0 + NW1 + 8) {
        const int sub = gw - NW0 - NW1;
        pos_wave8(sub, lane, logit0, pg0, coord0, wcls, wspos + sub, 64, 64, 64);
    } else {
        const int sub = gw - NW0 - NW1 - 8;
        pos_wave8(sub, lane, logit1, pg1, coord1, wcls, wspos + 8 + sub, 32, 32, 32);
    }
}

// ---------------------------------------------------------------------------
// Final reduction: one 1024-thread block sums all slots, writes out[0..3].
// ---------------------------------------------------------------------------
__global__ __launch_bounds__(1024)
void final_reduce(const float2* __restrict__ ws, float* __restrict__ out) {
    const float2* wsneg = ws;
    const float2* wspos = ws + NUNEG;
    float ln = 0.f, cn = 0.f, lp = 0.f, cp = 0.f;
    for (int i = threadIdx.x; i < NUNEG; i += 1024) {
        float2 v = wsneg[i]; ln += v.x; cn += v.y;
    }
    if (threadIdx.x < NWP) {
        float2 v = wspos[threadIdx.x]; lp = v.x; cp = v.y;
    }
#pragma unroll
    for (int off = 32; off > 0; off >>= 1) {
        ln += __shfl_down(ln, off); cn += __shfl_down(cn, off);
        lp += __shfl_down(lp, off); cp += __shfl_down(cp, off);
    }
    __shared__ float s[16][4];
    const int wv = threadIdx.x >> 6;
    if ((threadIdx.x & 63) == 0) {
        s[wv][0] = ln; s[wv][1] = cn; s[wv][2] = lp; s[wv][3] = cp;
    }
    __syncthreads();
    if (threadIdx.x == 0) {
        float a = 0.f, b = 0.f, c = 0.f, d = 0.f;
#pragma unroll
        for (int i = 0; i < 16; ++i) {
            a += s[i][0]; b += s[i][1]; c += s[i][2]; d += s[i][3];
        }
        out[0] = c;   // loss_pos
        out[1] = a;   // loss_neg
        out[2] = d;   // count_pos
        out[3] = b;   // count_neg
    }
}

extern "C" void kernel_launch(void* const* d_in, const int* in_sizes, int n_in,
                              void* d_out, int out_size, void* d_ws, size_t ws_size,
                              hipStream_t stream) {
    const float* logit0   = (const float*)d_in[0];
    const float* logit1   = (const float*)d_in[1];
    const float* prob_gt0 = (const float*)d_in[2];
    const float* prob_gt1 = (const float*)d_in[3];
    const int*   coord0   = (const int*)d_in[4];
    const int*   coord1   = (const int*)d_in[5];
    const float* wcls     = (const float*)d_in[6];
    float* out = (float*)d_out;
    float2* ws = (float2*)d_ws;

    mega_kernel<<<NBLK, 256, 0, stream>>>(
        logit0, logit1, prob_gt0, prob_gt1, coord0, coord1, wcls, ws);
    final_reduce<<<1, 1024, 0, stream>>>(ws, out);
}

// Round 9
// 105.906 us; speedup vs baseline: 1.0074x; 1.0051x over previous
//
#include <hip/hip_runtime.h>
#include <math.h>

#define NEG_INF (-INFINITY)

__device__ __forceinline__ float nll3(float l0, float l1, float l2) {
    float m = fmaxf(l0, fmaxf(l1, l2));
    float e0 = __expf(l0 - m);
    float e1 = __expf(l1 - m);
    float e2 = __expf(l2 - m);
    return __logf(e0 + e1 + e2) - (l0 - m);
}

// ---------------------------------------------------------------------------
// Depth-2-pipelined, vectorized, barrier/atomic-free neg-loss strip.
// Wave layout: NG = 64/(W/4) row-groups x LR = W/4 lanes; lane group g holds
// input row h0-1+g as a float4. Groups 0..NR-1 emit output rows h0..h0+NR-1.
// Register plane-sets A (consume now), B (+1), C (+2): step s consumes loads
// issued at step s-2, giving ~2 compute-steps of latency slack per wave.
// All loads unconditional (clamped addresses, -inf selection afterwards).
// ---------------------------------------------------------------------------
template<int W, int NR, int TD, int D, int H>
__device__ void neg_strip_p2(int uid, int lane,
                             const float* __restrict__ logit,
                             const float* __restrict__ pg,
                             float2* __restrict__ slot) {
    constexpr int LR = W / 4;          // lanes per row
    constexpr int NI = NR + 2;         // input rows used
    constexpr int HG = H / NR;
    constexpr int DT = D / TD;
    const int q = lane % LR;
    const int g = lane / LR;

    int t = uid;
    const int hg = t % HG; t /= HG;
    const int dt = t % DT; t /= DT;
    const int ba = t;                  // b*3 + a (A == 3)
    const int a = ba % 3, b = ba / 3;
    const int h0 = hg * NR, d0 = dt * TD;
    const int HW = H * W;

    const long S = (long)D * HW;
    const float* lb  = logit + ((long)b * 9 + a) * S;   // class-0 plane
    const long  cs   = 3 * S;                           // A*S
    const float* pgb = pg + (long)ba * S;

    const int jrow = h0 - 1 + g;
    const bool hv = (jrow >= 0) && (jrow < H) && (g < NI);
    const int hcl = min(max(jrow, 0), H - 1);
    const int rowoff = hcl * W + 4 * q;
    const int prowoff = (h0 + min(g, NR - 1)) * W + 4 * q;

    // plane-sets: A = consume at this step, B = +1, C = +2 (freshly loaded)
    float4 A0, A1, A2, B0, B1, B2, C0, C1, C2;
    float4 GA, GB, GC;
    bool vA, vB, vC;

    {   // prologue: planes d0-1 and d0
        const float* p = lb + (long)max(d0 - 1, 0) * HW + rowoff;
        A0 = *(const float4*)p;
        A1 = *(const float4*)(p + cs);
        A2 = *(const float4*)(p + 2 * cs);
        vA = (d0 - 1 >= 0);
        const float* p2 = lb + (long)d0 * HW + rowoff;
        B0 = *(const float4*)p2;
        B1 = *(const float4*)(p2 + cs);
        B2 = *(const float4*)(p2 + 2 * cs);
        vB = true;
        GA = make_float4(0.f, 0.f, 0.f, 0.f);   // pg consumed only from s>=2
        GB = make_float4(0.f, 0.f, 0.f, 0.f);
    }

    float vm0[4], vm1[4], cc1[4];
#pragma unroll
    for (int i = 0; i < 4; ++i) { vm0[i] = NEG_INF; vm1[i] = NEG_INF; cc1[i] = 0.f; }

    float loss = 0.f, cnt = 0.f;

#pragma unroll
    for (int s = 0; s <= TD + 1; ++s) {                 // s compile-time
        // ---- depth-2 prefetch: class plane d0+1+s, pg plane d0+s ----
        if (s <= TD - 1) {                              // compile-time guard
            const int pd = d0 + 1 + s;                  // may equal D -> clamp
            const float* p = lb + (long)min(pd, D - 1) * HW + rowoff;
            C0 = *(const float4*)p;
            C1 = *(const float4*)(p + cs);
            C2 = *(const float4*)(p + 2 * cs);
            vC = (pd < D);
            GC = *(const float4*)(pgb + (long)(d0 + s) * HW + prowoff); // < D
        } else {
            vC = false;
            C0 = C1 = C2 = make_float4(0.f, 0.f, 0.f, 0.f);
            GC = make_float4(0.f, 0.f, 0.f, 0.f);
        }

        // ---- nll of plane d0-1+s (set A) ----
        float nvv[4];
        {
            const bool vv = vA && hv;
            nvv[0] = vv ? nll3(A0.x, A1.x, A2.x) : NEG_INF;
            nvv[1] = vv ? nll3(A0.y, A1.y, A2.y) : NEG_INF;
            nvv[2] = vv ? nll3(A0.z, A1.z, A2.z) : NEG_INF;
            nvv[3] = vv ? nll3(A0.w, A1.w, A2.w) : NEG_INF;
        }

        // ---- in-row 3-wide max ----
        float le = __shfl(nvv[3], lane - 1);
        float re = __shfl(nvv[0], lane + 1);
        le = (q == 0)      ? NEG_INF : le;
        re = (q == LR - 1) ? NEG_INF : re;
        float rm[4];
        rm[0] = fmaxf(le,     fmaxf(nvv[0], nvv[1]));
        rm[1] = fmaxf(nvv[0], fmaxf(nvv[1], nvv[2]));
        rm[2] = fmaxf(nvv[1], fmaxf(nvv[2], nvv[3]));
        rm[3] = fmaxf(nvv[2], fmaxf(nvv[3], re));

        // ---- cross-row: group r gets rows r+1, r+2, center row r+1 ----
        float rmA[4], rmB[4], ctr[4];
#pragma unroll
        for (int i = 0; i < 4; ++i) {
            rmA[i] = __shfl(rm[i],  lane + LR);
            rmB[i] = __shfl(rm[i],  lane + 2 * LR);
            ctr[i] = __shfl(nvv[i], lane + LR);
        }

        // ---- 3-deep d-window + emit (center plane d0+s-2, pg in GA) ----
        const float pgv[4] = {GA.x, GA.y, GA.z, GA.w};
#pragma unroll
        for (int i = 0; i < 4; ++i) {
            float hw2 = fmaxf(rm[i], fmaxf(rmA[i], rmB[i]));
            if (s >= 2 && g < NR && pgv[i] == -1.0f) {
                float mp = fmaxf(vm0[i], fmaxf(vm1[i], hw2));
                if (mp == cc1[i]) {
                    float pn = __expf(-cc1[i]);
                    float wn = (1.f - pn) * (1.f - pn);
                    loss += cc1[i] * wn;
                    cnt  += wn;
                }
            }
            vm0[i] = vm1[i]; vm1[i] = hw2; cc1[i] = ctr[i];
        }

        // ---- rotate pipeline sets ----
        GA = GB; GB = GC;
        A0 = B0; A1 = B1; A2 = B2; vA = vB;
        B0 = C0; B1 = C1; B2 = C2; vB = vC;
    }

#pragma unroll
    for (int off = 32; off > 0; off >>= 1) {
        loss += __shfl_down(loss, off);
        cnt  += __shfl_down(cnt, off);
    }
    if (lane == 0) slot[uid] = make_float2(loss, cnt);
}

// ---------------------------------------------------------------------------
// Positive gathers: 8 waves per level, 1 item per lane (B*P = 512).
// ---------------------------------------------------------------------------
__device__ void pos_wave8(int sub, int lane,
                          const float* __restrict__ logit,
                          const float* __restrict__ prob_gt,
                          const int* __restrict__ coord,
                          const float* __restrict__ wcls,
                          float2* __restrict__ slot,
                          int D, int H, int W) {
    const int A = 3, P = 128;
    const long S = (long)D * H * W;
    const int i = sub * 64 + lane;          // < 512
    const int b = i / P;
    const int* c = coord + (long)i * 4;
    const int a = c[0];
    float loss = 0.f, cnt = 0.f;
    if (a > -1) {
        const int d = c[1], h = c[2], w = c[3];
        const long s = ((long)d * H + h) * W + w;
        const int cls = (int)prob_gt[((long)b * A + a) * S + s];
        const float* lp = logit + ((long)b * 3 * A + a) * S + s;
        float l0 = lp[0];
        float l1 = lp[(long)A * S];
        float l2 = lp[2L * A * S];
        float m = fmaxf(l0, fmaxf(l1, l2));
        float e0 = __expf(l0 - m);
        float e1 = __expf(l1 - m);
        float e2 = __expf(l2 - m);
        float lsum = __logf(e0 + e1 + e2);
        float lc = (cls == 0) ? l0 : ((cls == 1) ? l1 : l2);
        float lpc = (lc - m) - lsum;
        float pt = __expf(lpc);
        float wp = (1.f - pt) * (1.f - pt) * wcls[cls];
        loss = (-lpc) * wp;
        cnt = wp;
    }
#pragma unroll
    for (int off = 32; off > 0; off >>= 1) {
        loss += __shfl_down(loss, off);
        cnt  += __shfl_down(cnt, off);
    }
    if (lane == 0) *slot = make_float2(loss, cnt);
}

// ---------------------------------------------------------------------------
// Work split (wave-indexed, barrier-free):
//   L0: W=64, NR=2, TD=8 -> 12*32*8 = 3072 waves
//   L1: W=32, NR=4, TD=8 -> 12*8*4  =  384 waves
//   pos: 8 + 8 waves                     TOTAL 3472 -> 868 blocks
// ---------------------------------------------------------------------------
#define NW0 3072
#define NW1 384
#define NWP 16
#define NUNEG (NW0 + NW1)
#define TOTAL_WAVES (NW0 + NW1 + NWP)   // 3472 = 868 * 4

__global__ __launch_bounds__(256)
void mega_kernel(const float* __restrict__ logit0,
                 const float* __restrict__ logit1,
                 const float* __restrict__ pg0,
                 const float* __restrict__ pg1,
                 const int* __restrict__ coord0,
                 const int* __restrict__ coord1,
                 const float* __restrict__ wcls,
                 float2* __restrict__ ws) {
    const int gw = blockIdx.x * 4 + (threadIdx.x >> 6);
    const int lane = threadIdx.x & 63;
    float2* wsneg = ws;
    float2* wspos = ws + NUNEG;
    if (gw < NW0) {
        neg_strip_p2<64, 2, 8, 64, 64>(gw, lane, logit0, pg0, wsneg);
    } else if (gw < NW0 + NW1) {
        neg_strip_p2<32, 4, 8, 32, 32>(gw - NW0, lane, logit1, pg1, wsneg + NW0);
    } else if (gw < NW0 + NW1 + 8) {
        const int sub = gw - NW0 - NW1;
        pos_wave8(sub, lane, logit0, pg0, coord0, wcls, wspos + sub, 64, 64, 64);
    } else {
        const int sub = gw - NW0 - NW1 - 8;
        pos_wave8(sub, lane, logit1, pg1, coord1, wcls, wspos + 8 + sub, 32, 32, 32);
    }
}

// ---------------------------------------------------------------------------
// Final reduction: one 1024-thread block sums all slots, writes out[0..3].
// ---------------------------------------------------------------------------
__global__ __launch_bounds__(1024)
void final_reduce(const float2* __restrict__ ws, float* __restrict__ out) {
    const float2* wsneg = ws;
    const float2* wspos = ws + NUNEG;
    float ln = 0.f, cn = 0.f, lp = 0.f, cp = 0.f;
    for (int i = threadIdx.x; i < NUNEG; i += 1024) {
        float2 v = wsneg[i]; ln += v.x; cn += v.y;
    }
    if (threadIdx.x < NWP) {
        float2 v = wspos[threadIdx.x]; lp = v.x; cp = v.y;
    }
#pragma unroll
    for (int off = 32; off > 0; off >>= 1) {
        ln += __shfl_down(ln, off); cn += __shfl_down(cn, off);
        lp += __shfl_down(lp, off); cp += __shfl_down(cp, off);
    }
    __shared__ float s[16][4];
    const int wv = threadIdx.x >> 6;
    if ((threadIdx.x & 63) == 0) {
        s[wv][0] = ln; s[wv][1] = cn; s[wv][2] = lp; s[wv][3] = cp;
    }
    __syncthreads();
    if (threadIdx.x == 0) {
        float a = 0.f, b = 0.f, c = 0.f, d = 0.f;
#pragma unroll
        for (int i = 0; i < 16; ++i) {
            a += s[i][0]; b += s[i][1]; c += s[i][2]; d += s[i][3];
        }
        out[0] = c;   // loss_pos
        out[1] = a;   // loss_neg
        out[2] = d;   // count_pos
        out[3] = b;   // count_neg
    }
}

extern "C" void kernel_launch(void* const* d_in, const int* in_sizes, int n_in,
                              void* d_out, int out_size, void* d_ws, size_t ws_size,
                              hipStream_t stream) {
    const float* logit0   = (const float*)d_in[0];
    const float* logit1   = (const float*)d_in[1];
    const float* prob_gt0 = (const float*)d_in[2];
    const float* prob_gt1 = (const float*)d_in[3];
    const int*   coord0   = (const int*)d_in[4];
    const int*   coord1   = (const int*)d_in[5];
    const float* wcls     = (const float*)d_in[6];
    float* out = (float*)d_out;
    float2* ws = (float2*)d_ws;

    mega_kernel<<<TOTAL_WAVES / 4, 256, 0, stream>>>(
        logit0, logit1, prob_gt0, prob_gt1, coord0, coord1, wcls, ws);
    final_reduce<<<1, 1024, 0, stream>>>(ws, out);
}